// Round 3
// baseline (491.627 us; speedup 1.0000x reference)
//
#include <hip/hip_runtime.h>

#define BETA 0.9f
#define THRESH 1.0f

constexpr int Bsz  = 64;
constexpr int Din  = 1024;
constexpr int Dout = 1024;
constexpr int NBJ  = Bsz * Dout;        // 65536

// clang-native 4-float vector: required by __builtin_nontemporal_store
// (HIP's float4 is a struct wrapper it won't accept).
typedef float f4 __attribute__((ext_vector_type(4)));

// ---------------------------------------------------------------------------
// A: fused GEMM + LIF elementwise. (unchanged from R2 — clean A/B on kernel B)
// grid = Bsz * (Dout/64) = 1024 blocks x 256 threads.
// ---------------------------------------------------------------------------
__global__ __launch_bounds__(256) void gemm_lif(const float* __restrict__ x,
                                                const float* __restrict__ W,
                                                const float* __restrict__ bias,
                                                const float* __restrict__ u0,
                                                const float* __restrict__ E_b,
                                                float* __restrict__ out_spk,
                                                float* __restrict__ out_u,
                                                float* __restrict__ out_Eb,
                                                float* __restrict__ one_m_ws) {
    __shared__ float red[4][64];
    const int blk = blockIdx.x;
    const int b   = blk >> 4;           // sample 0..63
    const int jg  = blk & 15;           // 64-column group
    const int t   = threadIdx.x;
    const int jl  = t & 63;
    const int ks  = t >> 6;             // k-slice == wave id
    const int j   = (jg << 6) + jl;

    const float* xr = x + b * Din + (ks << 8);
    const float* Wc = W + (size_t)(ks << 8) * Dout + j;

    float acc = 0.f;
#pragma unroll 16
    for (int k = 0; k < 256; ++k)
        acc = fmaf(xr[k], Wc[(size_t)k * Dout], acc);

    red[ks][jl] = acc;
    __syncthreads();

    if (t < 64) {
        const int idx = b * Dout + j;
        float I   = red[0][t] + red[1][t] + red[2][t] + red[3][t] + bias[j];
        float v   = fmaf(BETA, u0[idx], I);
        float vt  = v - THRESH;
        float spk = vt > 0.f ? 1.f : 0.f;
        float a   = 1.f + fabsf(vt);
        float om  = 1.f - THRESH / (a * a);

        out_spk[idx]  = spk;
        out_u[idx]    = v - THRESH * spk;
        out_Eb[idx]   = om * fmaf(BETA, E_b[idx], 1.f);
        one_m_ws[idx] = om;
    }
}

// ---------------------------------------------------------------------------
// B: the 512 MB E_W stream — canonical m13-style grid-stride copy shape.
// E_W_new[b,i,j] = one_m[b,j] * (BETA*E_W[b,i,j] + x[b,i])
//
// R2 post-mortem: per-thread 16-row walk at VGPR=32 ran at 2.4 TB/s (30% peak)
// — compiler couldn't keep loads in flight, and each wave hopped 4 KB windows.
// Now: 2048 blocks x 256 threads, each iteration processes 4 INDEPENDENT
// float4s separated by the full grid stride (S = 512K vec4 = 8 MB). All 4
// loads issue back-to-back before any wait (guaranteed MLP), every load/store
// instruction is a contiguous 1 KB per wave, and at any instant the whole
// grid sweeps 4 contiguous 8 MB windows. 8 outer iterations total.
// one_m (1 MB, L2-resident) and x (256 KB) reloaded per element — R2 proved
// hoisting them buys nothing; they're not the bottleneck stream.
// ---------------------------------------------------------------------------
constexpr unsigned NV4   = (unsigned)Bsz * Din * Dout / 4;  // 16777216 vec4
constexpr unsigned EW_TH = 2048u * 256u;                    // 524288 threads
constexpr unsigned EW_IT = NV4 / (EW_TH * 4u);              // 8 outer iters

__global__ __launch_bounds__(256) void ew_update(const float* __restrict__ E_W,
                                                 const float* __restrict__ x,
                                                 const float* __restrict__ one_m,
                                                 float* __restrict__ out_EW) {
    const unsigned tid = blockIdx.x * 256u + threadIdx.x;
    const f4* __restrict__ src = (const f4*)E_W;
    f4* __restrict__       dst = (f4*)out_EW;
    const f4* __restrict__ om4 = (const f4*)one_m;

    unsigned base = tid;                 // 4 streams: base + {0,1,2,3}*EW_TH
#pragma unroll
    for (unsigned it = 0; it < EW_IT; ++it, base += 4u * EW_TH) {
        const unsigned v0 = base, v1 = base + EW_TH, v2 = base + 2u * EW_TH,
                       v3 = base + 3u * EW_TH;
        // 4 independent HBM loads issued before any dependent use
        const f4 e0 = src[v0];
        const f4 e1 = src[v1];
        const f4 e2 = src[v2];
        const f4 e3 = src[v3];

        // per-stream (b, i, jv) decode — pure shifts/ands
        const unsigned b0 = v0 >> 18, b1 = v1 >> 18, b2 = v2 >> 18, b3 = v3 >> 18;
        const f4 m0 = om4[(b0 << 8) | (v0 & 255u)];
        const f4 m1 = om4[(b1 << 8) | (v1 & 255u)];
        const f4 m2 = om4[(b2 << 8) | (v2 & 255u)];
        const f4 m3 = om4[(b3 << 8) | (v3 & 255u)];
        const float x0 = x[(b0 << 10) | ((v0 >> 8) & 1023u)];
        const float x1 = x[(b1 << 10) | ((v1 >> 8) & 1023u)];
        const float x2 = x[(b2 << 10) | ((v2 >> 8) & 1023u)];
        const float x3 = x[(b3 << 10) | ((v3 >> 8) & 1023u)];

        f4 r0, r1, r2, r3;
        r0.x = m0.x * fmaf(BETA, e0.x, x0); r0.y = m0.y * fmaf(BETA, e0.y, x0);
        r0.z = m0.z * fmaf(BETA, e0.z, x0); r0.w = m0.w * fmaf(BETA, e0.w, x0);
        r1.x = m1.x * fmaf(BETA, e1.x, x1); r1.y = m1.y * fmaf(BETA, e1.y, x1);
        r1.z = m1.z * fmaf(BETA, e1.z, x1); r1.w = m1.w * fmaf(BETA, e1.w, x1);
        r2.x = m2.x * fmaf(BETA, e2.x, x2); r2.y = m2.y * fmaf(BETA, e2.y, x2);
        r2.z = m2.z * fmaf(BETA, e2.z, x2); r2.w = m2.w * fmaf(BETA, e2.w, x2);
        r3.x = m3.x * fmaf(BETA, e3.x, x3); r3.y = m3.y * fmaf(BETA, e3.y, x3);
        r3.z = m3.z * fmaf(BETA, e3.z, x3); r3.w = m3.w * fmaf(BETA, e3.w, x3);

        __builtin_nontemporal_store(r0, &dst[v0]);
        __builtin_nontemporal_store(r1, &dst[v1]);
        __builtin_nontemporal_store(r2, &dst[v2]);
        __builtin_nontemporal_store(r3, &dst[v3]);
    }
}

extern "C" void kernel_launch(void* const* d_in, const int* in_sizes, int n_in,
                              void* d_out, int out_size, void* d_ws, size_t ws_size,
                              hipStream_t stream) {
    const float* x    = (const float*)d_in[0];
    const float* W    = (const float*)d_in[1];
    const float* bias = (const float*)d_in[2];
    const float* u0   = (const float*)d_in[3];
    const float* E_W  = (const float*)d_in[4];
    const float* E_b  = (const float*)d_in[5];

    float* out     = (float*)d_out;
    float* out_spk = out;                       // [64,1024]
    float* out_u   = out + NBJ;                 // [64,1024]
    float* out_EW  = out + 2 * NBJ;             // [64,1024,1024]
    float* out_Eb  = out + 2 * NBJ + (size_t)Bsz * Din * Dout;  // [64,1024]

    float* one_m = (float*)d_ws;                // 256 KB

    gemm_lif<<<Bsz * (Dout / 64), 256, 0, stream>>>(x, W, bias, u0, E_b,
                                                    out_spk, out_u, out_Eb, one_m);
    ew_update<<<2048, 256, 0, stream>>>(E_W, x, one_m, out_EW);
}

// Round 4
// 481.037 us; speedup vs baseline: 1.0220x; 1.0220x over previous
//
#include <hip/hip_runtime.h>

#define BETA 0.9f
#define THRESH 1.0f

constexpr int Bsz  = 64;
constexpr int Din  = 1024;
constexpr int Dout = 1024;
constexpr int NBJ  = Bsz * Dout;        // 65536

typedef float f4 __attribute__((ext_vector_type(4)));

// ---------------------------------------------------------------------------
// A: fused GEMM + LIF elementwise. (unchanged — A/B isolation on kernel B)
// grid = Bsz * (Dout/64) = 1024 blocks x 256 threads.
// ---------------------------------------------------------------------------
__global__ __launch_bounds__(256) void gemm_lif(const float* __restrict__ x,
                                                const float* __restrict__ W,
                                                const float* __restrict__ bias,
                                                const float* __restrict__ u0,
                                                const float* __restrict__ E_b,
                                                float* __restrict__ out_spk,
                                                float* __restrict__ out_u,
                                                float* __restrict__ out_Eb,
                                                float* __restrict__ one_m_ws) {
    __shared__ float red[4][64];
    const int blk = blockIdx.x;
    const int b   = blk >> 4;           // sample 0..63
    const int jg  = blk & 15;           // 64-column group
    const int t   = threadIdx.x;
    const int jl  = t & 63;
    const int ks  = t >> 6;             // k-slice == wave id
    const int j   = (jg << 6) + jl;

    const float* xr = x + b * Din + (ks << 8);
    const float* Wc = W + (size_t)(ks << 8) * Dout + j;

    float acc = 0.f;
#pragma unroll 16
    for (int k = 0; k < 256; ++k)
        acc = fmaf(xr[k], Wc[(size_t)k * Dout], acc);

    red[ks][jl] = acc;
    __syncthreads();

    if (t < 64) {
        const int idx = b * Dout + j;
        float I   = red[0][t] + red[1][t] + red[2][t] + red[3][t] + bias[j];
        float v   = fmaf(BETA, u0[idx], I);
        float vt  = v - THRESH;
        float spk = vt > 0.f ? 1.f : 0.f;
        float a   = 1.f + fabsf(vt);
        float om  = 1.f - THRESH / (a * a);

        out_spk[idx]  = spk;
        out_u[idx]    = v - THRESH * spk;
        out_Eb[idx]   = om * fmaf(BETA, E_b[idx], 1.f);
        one_m_ws[idx] = om;
    }
}

// ---------------------------------------------------------------------------
// B: the 512 MB E_W stream.  Identical structure to R3 (grid-stride, 4
// independent full-grid-stride f4 streams per iteration, 2048x256).
// SINGLE AXIS CHANGE vs R3: plain stores instead of __builtin_nontemporal_store.
// Evidence: R2 (16-row walk + nt) and R3 (grid-stride + nt) both ~2.2 TB/s;
// every plain-store stream on this chip (fillBuffer 6.5 TB/s, m13 copy
// 6.29 TB/s, R0's ew_update) is 2-3x faster. nt (no-allocate) store path is
// the suspected throttle.
// ---------------------------------------------------------------------------
constexpr unsigned NV4   = (unsigned)Bsz * Din * Dout / 4;  // 16777216 vec4
constexpr unsigned EW_TH = 2048u * 256u;                    // 524288 threads
constexpr unsigned EW_IT = NV4 / (EW_TH * 4u);              // 8 outer iters

__global__ __launch_bounds__(256) void ew_update(const float* __restrict__ E_W,
                                                 const float* __restrict__ x,
                                                 const float* __restrict__ one_m,
                                                 float* __restrict__ out_EW) {
    const unsigned tid = blockIdx.x * 256u + threadIdx.x;
    const f4* __restrict__ src = (const f4*)E_W;
    f4* __restrict__       dst = (f4*)out_EW;
    const f4* __restrict__ om4 = (const f4*)one_m;

    unsigned base = tid;                 // 4 streams: base + {0,1,2,3}*EW_TH
#pragma unroll
    for (unsigned it = 0; it < EW_IT; ++it, base += 4u * EW_TH) {
        const unsigned v0 = base, v1 = base + EW_TH, v2 = base + 2u * EW_TH,
                       v3 = base + 3u * EW_TH;
        // 4 independent HBM loads issued before any dependent use
        const f4 e0 = src[v0];
        const f4 e1 = src[v1];
        const f4 e2 = src[v2];
        const f4 e3 = src[v3];

        const unsigned b0 = v0 >> 18, b1 = v1 >> 18, b2 = v2 >> 18, b3 = v3 >> 18;
        const f4 m0 = om4[(b0 << 8) | (v0 & 255u)];
        const f4 m1 = om4[(b1 << 8) | (v1 & 255u)];
        const f4 m2 = om4[(b2 << 8) | (v2 & 255u)];
        const f4 m3 = om4[(b3 << 8) | (v3 & 255u)];
        const float x0 = x[(b0 << 10) | ((v0 >> 8) & 1023u)];
        const float x1 = x[(b1 << 10) | ((v1 >> 8) & 1023u)];
        const float x2 = x[(b2 << 10) | ((v2 >> 8) & 1023u)];
        const float x3 = x[(b3 << 10) | ((v3 >> 8) & 1023u)];

        f4 r0, r1, r2, r3;
        r0.x = m0.x * fmaf(BETA, e0.x, x0); r0.y = m0.y * fmaf(BETA, e0.y, x0);
        r0.z = m0.z * fmaf(BETA, e0.z, x0); r0.w = m0.w * fmaf(BETA, e0.w, x0);
        r1.x = m1.x * fmaf(BETA, e1.x, x1); r1.y = m1.y * fmaf(BETA, e1.y, x1);
        r1.z = m1.z * fmaf(BETA, e1.z, x1); r1.w = m1.w * fmaf(BETA, e1.w, x1);
        r2.x = m2.x * fmaf(BETA, e2.x, x2); r2.y = m2.y * fmaf(BETA, e2.y, x2);
        r2.z = m2.z * fmaf(BETA, e2.z, x2); r2.w = m2.w * fmaf(BETA, e2.w, x2);
        r3.x = m3.x * fmaf(BETA, e3.x, x3); r3.y = m3.y * fmaf(BETA, e3.y, x3);
        r3.z = m3.z * fmaf(BETA, e3.z, x3); r3.w = m3.w * fmaf(BETA, e3.w, x3);

        dst[v0] = r0;          // plain stores — the single change vs R3
        dst[v1] = r1;
        dst[v2] = r2;
        dst[v3] = r3;
    }
}

extern "C" void kernel_launch(void* const* d_in, const int* in_sizes, int n_in,
                              void* d_out, int out_size, void* d_ws, size_t ws_size,
                              hipStream_t stream) {
    const float* x    = (const float*)d_in[0];
    const float* W    = (const float*)d_in[1];
    const float* bias = (const float*)d_in[2];
    const float* u0   = (const float*)d_in[3];
    const float* E_W  = (const float*)d_in[4];
    const float* E_b  = (const float*)d_in[5];

    float* out     = (float*)d_out;
    float* out_spk = out;                       // [64,1024]
    float* out_u   = out + NBJ;                 // [64,1024]
    float* out_EW  = out + 2 * NBJ;             // [64,1024,1024]
    float* out_Eb  = out + 2 * NBJ + (size_t)Bsz * Din * Dout;  // [64,1024]

    float* one_m = (float*)d_ws;                // 256 KB

    gemm_lif<<<Bsz * (Dout / 64), 256, 0, stream>>>(x, W, bias, u0, E_b,
                                                    out_spk, out_u, out_Eb, one_m);
    ew_update<<<2048, 256, 0, stream>>>(E_W, x, one_m, out_EW);
}